// Round 10
// baseline (2101.204 us; speedup 1.0000x reference)
//
#include <hip/hip_runtime.h>
#include <hip/hip_bf16.h>

#define N_NODES 100000
#define N_EDGES 1600000
#define NFEAT   200
#define NHID    128
#define NOUT    64
#define BN_EPS  1e-5f

static constexpr int SCAN_NB = (N_NODES + 255) / 256;   // 391 blocks in level-1 scan

// ---------------------------------------------------------------- init
__global__ __launch_bounds__(256) void init_kernel(int* counts, float* deg, float* stats)
{
    int i = blockIdx.x * 256 + threadIdx.x;
    if (i <= N_NODES) counts[i] = 0;
    if (i <  N_NODES) deg[i]    = 1.0f;          // self-loop weight
    if (i <  512)     stats[i]  = 0.0f;          // stats0 (256) + stats1 (256)
}

// ------------------------------------------------------------ histogram
__global__ __launch_bounds__(256) void hist_kernel(const int* __restrict__ adj,
                                                   const float* __restrict__ wt,
                                                   int* __restrict__ counts,
                                                   float* __restrict__ deg)
{
    int e = blockIdx.x * 256 + threadIdx.x;
    if (e >= N_EDGES) return;
    int d = adj[N_EDGES + e];                     // dst row
    atomicAdd(&counts[d], 1);
    atomicAdd(&deg[d], wt[e]);
}

// ------------------------------------------------------- scan level 1
__global__ __launch_bounds__(256) void scan_block(const int* __restrict__ counts,
                                                  int* __restrict__ rowptr,
                                                  int* __restrict__ bsums)
{
    __shared__ int s[256];
    int t = threadIdx.x;
    int i = blockIdx.x * 256 + t;
    int v = (i < N_NODES) ? counts[i] : 0;
    s[t] = v; __syncthreads();
    #pragma unroll
    for (int off = 1; off < 256; off <<= 1) {
        int x = (t >= off) ? s[t - off] : 0;
        __syncthreads();
        s[t] += x;
        __syncthreads();
    }
    if (i < N_NODES) rowptr[i] = s[t] - v;        // block-local exclusive
    if (t == 255) bsums[blockIdx.x] = s[255];
}

// ------------------------------------------------------- scan level 2
__global__ __launch_bounds__(512) void scan_top(int* bsums)
{
    __shared__ int s[512];
    int t = threadIdx.x;
    int v = (t < SCAN_NB) ? bsums[t] : 0;
    s[t] = v; __syncthreads();
    #pragma unroll
    for (int off = 1; off < 512; off <<= 1) {
        int x = (t >= off) ? s[t - off] : 0;
        __syncthreads();
        s[t] += x;
        __syncthreads();
    }
    if (t < SCAN_NB) bsums[t] = s[t] - v;         // exclusive
}

// --------------------------------------- scan add + cursor + dinv fuse
__global__ __launch_bounds__(256) void scan_add(int* __restrict__ rowptr,
                                                const int* __restrict__ bsums,
                                                int* __restrict__ cursor,
                                                float* __restrict__ deg)
{
    int i = blockIdx.x * 256 + threadIdx.x;
    if (i < N_NODES) {
        int r = rowptr[i] + bsums[i >> 8];
        rowptr[i] = r;
        cursor[i] = r;
        float d = deg[i];
        deg[i] = (d > 0.f) ? rsqrtf(d) : 0.f;     // deg -> dinv in place
    }
    if (i == 0) rowptr[N_NODES] = N_EDGES;
}

// ------------------------------------------------------------ CSR fill
__global__ __launch_bounds__(256) void fill_kernel(const int* __restrict__ adj,
                                                   const float* __restrict__ wt,
                                                   const float* __restrict__ dinv,
                                                   int* __restrict__ cursor,
                                                   int2* __restrict__ col)
{
    int e = blockIdx.x * 256 + threadIdx.x;
    if (e >= N_EDGES) return;
    int s = adj[e];
    int d = adj[N_EDGES + e];
    int pos = atomicAdd(&cursor[d], 1);
    int2 c;
    c.x = s;
    c.y = __float_as_int(dinv[s] * wt[e] * dinv[d]);
    col[pos] = c;
}

// ------------------------------------------------------------- GEMM v2
// C[M,NC] = A[M,K] @ W[K,NC] (+bias if non-null) (+relu if RELU).
// A is NOT staged in LDS: threads sharing a row-group issue identical
// (broadcast) float4 global loads -> 1 coalesced transaction, L1/L2-served.
// Only W lives in LDS (BKx128 = 32KB or BKx64 = 16KB) -> high occupancy,
// and all LDS traffic is ds_read_b128 (fc1 round-7 kernel was LDS-bound
// on per-element ds_read_b32: 70 LDS cyc vs 32 VALU cyc per kk per wave).
template<int NC, bool RELU>
__global__ __launch_bounds__(256) void gemm2(const float* __restrict__ A,
                                             const float* __restrict__ W,
                                             const float* __restrict__ bias,
                                             float* __restrict__ C,
                                             int M, int K)
{
    constexpr int BK   = 64;
    constexpr int COLG = NC / 8;             // 16 (NC=128) / 8 (NC=64)
    constexpr int RG   = 256 / COLG;         // 16 / 32
    constexpr int BM   = 128;
    constexpr int RPT  = BM / RG;            // 8 / 4
    __shared__ float w_t[BK][NC];

    const int t    = threadIdx.x;
    const int m0   = blockIdx.x * BM;
    const int g    = t % COLG;
    const int c_lo = g * 4;
    const int c_hi = NC / 2 + c_lo;
    const int r0   = (t / COLG) * RPT;

    bool rowok[RPT];
    const float* arow[RPT];
    #pragma unroll
    for (int j = 0; j < RPT; ++j) {
        int m = m0 + r0 + j;
        rowok[j] = (m < M);
        arow[j]  = A + (size_t)(rowok[j] ? m : 0) * K;
    }

    float acc[RPT][8];
    #pragma unroll
    for (int j = 0; j < RPT; ++j)
        #pragma unroll
        for (int i = 0; i < 8; ++i) acc[j][i] = 0.f;

    for (int k0 = 0; k0 < K; k0 += BK) {
        __syncthreads();
        constexpr int WF4 = BK * NC / 1024;  // float4 stores per thread: 8 / 4
        #pragma unroll
        for (int i = 0; i < WF4; ++i) {
            int idx = t + i * 256;
            int kr  = idx / (NC / 4);
            int c4  = (idx % (NC / 4)) * 4;
            float4 v = make_float4(0.f, 0.f, 0.f, 0.f);
            if (k0 + kr < K) v = *(const float4*)&W[(size_t)(k0 + kr) * NC + c4];
            *(float4*)&w_t[kr][c4] = v;
        }
        __syncthreads();

        #pragma unroll 4
        for (int q = 0; q < BK / 4; ++q) {
            int k = k0 + q * 4;                       // K % 4 == 0 always here
            float4 a[RPT];
            if (k < K) {
                #pragma unroll
                for (int j = 0; j < RPT; ++j)
                    a[j] = rowok[j] ? *(const float4*)&arow[j][k]
                                    : make_float4(0.f, 0.f, 0.f, 0.f);
            } else {
                #pragma unroll
                for (int j = 0; j < RPT; ++j) a[j] = make_float4(0.f, 0.f, 0.f, 0.f);
            }
            #pragma unroll
            for (int u = 0; u < 4; ++u) {
                float4 w0 = *(const float4*)&w_t[q * 4 + u][c_lo];
                float4 w1 = *(const float4*)&w_t[q * 4 + u][c_hi];
                #pragma unroll
                for (int j = 0; j < RPT; ++j) {
                    float av = ((const float*)&a[j])[u];
                    acc[j][0] += av * w0.x; acc[j][1] += av * w0.y;
                    acc[j][2] += av * w0.z; acc[j][3] += av * w0.w;
                    acc[j][4] += av * w1.x; acc[j][5] += av * w1.y;
                    acc[j][6] += av * w1.z; acc[j][7] += av * w1.w;
                }
            }
        }
    }

    float4 b0 = make_float4(0.f, 0.f, 0.f, 0.f);
    float4 b1 = make_float4(0.f, 0.f, 0.f, 0.f);
    if (bias) {
        b0 = *(const float4*)&bias[c_lo];
        b1 = *(const float4*)&bias[c_hi];
    }
    #pragma unroll
    for (int j = 0; j < RPT; ++j) {
        int m = m0 + r0 + j;
        if (m >= M) continue;
        float4 o0 = make_float4(acc[j][0] + b0.x, acc[j][1] + b0.y,
                                acc[j][2] + b0.z, acc[j][3] + b0.w);
        float4 o1 = make_float4(acc[j][4] + b1.x, acc[j][5] + b1.y,
                                acc[j][6] + b1.z, acc[j][7] + b1.w);
        if (RELU) {
            o0.x = fmaxf(o0.x, 0.f); o0.y = fmaxf(o0.y, 0.f);
            o0.z = fmaxf(o0.z, 0.f); o0.w = fmaxf(o0.w, 0.f);
            o1.x = fmaxf(o1.x, 0.f); o1.y = fmaxf(o1.y, 0.f);
            o1.z = fmaxf(o1.z, 0.f); o1.w = fmaxf(o1.w, 0.f);
        }
        *(float4*)&C[(size_t)m * NC + c_lo] = o0;
        *(float4*)&C[(size_t)m * NC + c_hi] = o1;
    }
}

// ----------------------------------------- fc1 concat GEMM (BN folded)
// C = relu([x | h1 | h2] @ Wf + bf); Wf rows for h1/h2 pre-scaled by BN
// scale, bf carries fc1_b + shift@W terms. Segment choice is uniform per
// k-quad (boundaries 200/328/456 are %4==0).
__global__ __launch_bounds__(256) void gemm_cat(const float* __restrict__ x,
                                                const float* __restrict__ h1,
                                                const float* __restrict__ h2,
                                                const float* __restrict__ Wf,
                                                const float* __restrict__ bf,
                                                float* __restrict__ C, int M)
{
    constexpr int NC = NHID, BK = 64, KTOT = NFEAT + 2 * NHID;  // 456
    constexpr int COLG = 16, RPT = 8, BM = 128;
    __shared__ float w_t[BK][NC];

    const int t    = threadIdx.x;
    const int m0   = blockIdx.x * BM;
    const int g    = t % COLG;
    const int c_lo = g * 4;
    const int c_hi = NC / 2 + c_lo;
    const int r0   = (t / COLG) * RPT;

    bool rowok[RPT];
    int  mrow[RPT];
    #pragma unroll
    for (int j = 0; j < RPT; ++j) {
        int m = m0 + r0 + j;
        rowok[j] = (m < M);
        mrow[j]  = rowok[j] ? m : 0;
    }

    float acc[RPT][8];
    #pragma unroll
    for (int j = 0; j < RPT; ++j)
        #pragma unroll
        for (int i = 0; i < 8; ++i) acc[j][i] = 0.f;

    for (int k0 = 0; k0 < 512; k0 += BK) {
        __syncthreads();
        #pragma unroll
        for (int i = 0; i < 8; ++i) {
            int idx = t + i * 256;
            int kr  = idx / (NC / 4);
            int c4  = (idx % (NC / 4)) * 4;
            float4 v = make_float4(0.f, 0.f, 0.f, 0.f);
            if (k0 + kr < KTOT) v = *(const float4*)&Wf[(size_t)(k0 + kr) * NC + c4];
            *(float4*)&w_t[kr][c4] = v;
        }
        __syncthreads();

        #pragma unroll 4
        for (int q = 0; q < BK / 4; ++q) {
            int kc = k0 + q * 4;
            float4 a[RPT];
            if (kc < KTOT) {
                const float* src; int kk, ld;
                if (kc < NFEAT)             { src = x;  kk = kc;               ld = NFEAT; }
                else if (kc < NFEAT + NHID) { src = h1; kk = kc - NFEAT;       ld = NHID;  }
                else                        { src = h2; kk = kc - NFEAT - NHID; ld = NHID; }
                #pragma unroll
                for (int j = 0; j < RPT; ++j)
                    a[j] = rowok[j] ? *(const float4*)&src[(size_t)mrow[j] * ld + kk]
                                    : make_float4(0.f, 0.f, 0.f, 0.f);
            } else {
                #pragma unroll
                for (int j = 0; j < RPT; ++j) a[j] = make_float4(0.f, 0.f, 0.f, 0.f);
            }
            #pragma unroll
            for (int u = 0; u < 4; ++u) {
                float4 w0 = *(const float4*)&w_t[q * 4 + u][c_lo];
                float4 w1 = *(const float4*)&w_t[q * 4 + u][c_hi];
                #pragma unroll
                for (int j = 0; j < RPT; ++j) {
                    float av = ((const float*)&a[j])[u];
                    acc[j][0] += av * w0.x; acc[j][1] += av * w0.y;
                    acc[j][2] += av * w0.z; acc[j][3] += av * w0.w;
                    acc[j][4] += av * w1.x; acc[j][5] += av * w1.y;
                    acc[j][6] += av * w1.z; acc[j][7] += av * w1.w;
                }
            }
        }
    }

    float4 b0 = *(const float4*)&bf[c_lo];
    float4 b1 = *(const float4*)&bf[c_hi];
    #pragma unroll
    for (int j = 0; j < RPT; ++j) {
        int m = m0 + r0 + j;
        if (m >= M) continue;
        float4 o0 = make_float4(fmaxf(acc[j][0] + b0.x, 0.f), fmaxf(acc[j][1] + b0.y, 0.f),
                                fmaxf(acc[j][2] + b0.z, 0.f), fmaxf(acc[j][3] + b0.w, 0.f));
        float4 o1 = make_float4(fmaxf(acc[j][4] + b1.x, 0.f), fmaxf(acc[j][5] + b1.y, 0.f),
                                fmaxf(acc[j][6] + b1.z, 0.f), fmaxf(acc[j][7] + b1.w, 0.f));
        *(float4*)&C[(size_t)m * NC + c_lo] = o0;
        *(float4*)&C[(size_t)m * NC + c_hi] = o1;
    }
}

// ----------------------------- BN fold for conv2: W2f = diag(sc1)@W2,
// c2[c] = sum_k sh1[k]*W2[k][c]  (constant row, added as GEMM bias)
__global__ __launch_bounds__(128) void wfold2(const float* __restrict__ W2,
                                              const float* __restrict__ scsh1,
                                              float* __restrict__ W2f,
                                              float* __restrict__ c2)
{
    int c = threadIdx.x;                       // 0..127, single block
    float acc = 0.f;
    for (int k = 0; k < NHID; ++k) {
        float w = W2[k * NHID + c];
        W2f[k * NHID + c] = scsh1[k] * w;
        acc += scsh1[NHID + k] * w;
    }
    c2[c] = acc;
}

// ----------------------------- BN fold for fc1 concat weight + bias
__global__ __launch_bounds__(128) void fc1fold(const float* __restrict__ Wc,
                                               const float* __restrict__ fc1b,
                                               const float* __restrict__ scsh1,
                                               const float* __restrict__ scsh2,
                                               float* __restrict__ Wf,
                                               float* __restrict__ bf)
{
    int c = threadIdx.x;                       // 0..127, grid = 2
    if (blockIdx.x == 0) {                     // copy x-rows unchanged
        for (int k = 0; k < NFEAT; ++k)
            Wf[(size_t)k * NHID + c] = Wc[(size_t)k * NHID + c];
    } else {                                   // scale h-rows, build bias
        float acc = fc1b[c];
        for (int k = 0; k < NHID; ++k) {
            float w = Wc[(size_t)(NFEAT + k) * NHID + c];
            Wf[(size_t)(NFEAT + k) * NHID + c] = scsh1[k] * w;
            acc += scsh1[NHID + k] * w;
        }
        for (int k = 0; k < NHID; ++k) {
            float w = Wc[(size_t)(NFEAT + NHID + k) * NHID + c];
            Wf[(size_t)(NFEAT + NHID + k) * NHID + c] = scsh2[k] * w;
            acc += scsh2[NHID + k] * w;
        }
        bf[c] = acc;
    }
}

// --------------------------------------------------------- aggregation
// out[n,f] = relu( dinv[n]^2 * h[n,f] + sum_e norm[e]*h[src[e],f] + b[f] )
__global__ __launch_bounds__(256) void agg_kernel(const float* __restrict__ h,
                                                  const float* __restrict__ bias,
                                                  const float* __restrict__ dinv,
                                                  const int* __restrict__ rowptr,
                                                  const int2* __restrict__ col,
                                                  float* __restrict__ out)
{
    int node = blockIdx.x * 4 + (threadIdx.x >> 6);
    if (node >= N_NODES) return;
    int lane = threadIdx.x & 63;
    int f0 = lane * 2;

    float di = dinv[node];
    float2 hv = *(const float2*)&h[(size_t)node * NHID + f0];
    float ax = di * di * hv.x;
    float ay = di * di * hv.y;

    int e = rowptr[node], end = rowptr[node + 1];
    for (; e + 4 <= end; e += 4) {
        int2 c0 = col[e],     c1 = col[e + 1];
        int2 c2 = col[e + 2], c3 = col[e + 3];
        float2 v0 = *(const float2*)&h[(size_t)c0.x * NHID + f0];
        float2 v1 = *(const float2*)&h[(size_t)c1.x * NHID + f0];
        float2 v2 = *(const float2*)&h[(size_t)c2.x * NHID + f0];
        float2 v3 = *(const float2*)&h[(size_t)c3.x * NHID + f0];
        float n0 = __int_as_float(c0.y), n1 = __int_as_float(c1.y);
        float n2 = __int_as_float(c2.y), n3 = __int_as_float(c3.y);
        ax += n0 * v0.x + n1 * v1.x + n2 * v2.x + n3 * v3.x;
        ay += n0 * v0.y + n1 * v1.y + n2 * v2.y + n3 * v3.y;
    }
    for (; e < end; ++e) {
        int2 c = col[e];
        float2 v = *(const float2*)&h[(size_t)c.x * NHID + f0];
        float n = __int_as_float(c.y);
        ax += n * v.x;
        ay += n * v.y;
    }
    float2 b = *(const float2*)&bias[f0];
    float2 o;
    o.x = fmaxf(ax + b.x, 0.f);
    o.y = fmaxf(ay + b.y, 0.f);
    *(float2*)&out[(size_t)node * NHID + f0] = o;
}

// --------------------------------------------------------------- stats
__global__ __launch_bounds__(256) void stats_kernel(const float* __restrict__ h,
                                                    float* __restrict__ st)
{
    __shared__ float ls[256], ls2[256];
    int t = threadIdx.x;
    int c = t & 127, half = t >> 7;
    float s = 0.f, s2 = 0.f;
    for (int r = blockIdx.x * 2 + half; r < N_NODES; r += gridDim.x * 2) {
        float v = h[(size_t)r * NHID + c];
        s += v; s2 += v * v;
    }
    ls[t] = s; ls2[t] = s2; __syncthreads();
    if (half == 0) {
        s  += ls[t + 128];
        s2 += ls2[t + 128];
        atomicAdd(&st[c], s);
        atomicAdd(&st[128 + c], s2);
    }
}

// --------------------------------------------------------- bn finalize
__global__ __launch_bounds__(128) void bn_finalize(const float* __restrict__ st,
                                                   const float* __restrict__ g,
                                                   const float* __restrict__ beta,
                                                   float* __restrict__ scsh)
{
    int c = threadIdx.x;
    float mean = st[c] / (float)N_NODES;
    float var  = st[128 + c] / (float)N_NODES - mean * mean;
    float inv  = rsqrtf(var + BN_EPS);
    float sc   = g[c] * inv;
    scsh[c]        = sc;
    scsh[NHID + c] = beta[c] - mean * sc;
}

// ---------------------------------------------------------------- host
extern "C" void kernel_launch(void* const* d_in, const int* in_sizes, int n_in,
                              void* d_out, int out_size, void* d_ws, size_t ws_size,
                              hipStream_t stream)
{
    const float* x     = (const float*)d_in[0];
    const int*   adj   = (const int*)d_in[1];
    const float* wt    = (const float*)d_in[2];
    const float* W1    = (const float*)d_in[3];
    const float* b1    = (const float*)d_in[4];
    const float* W2    = (const float*)d_in[5];
    const float* b2    = (const float*)d_in[6];
    const float* g1    = (const float*)d_in[7];
    const float* beta1 = (const float*)d_in[8];
    const float* g2    = (const float*)d_in[9];
    const float* beta2 = (const float*)d_in[10];
    const float* fc1W  = (const float*)d_in[11];
    const float* fc1b  = (const float*)d_in[12];
    const float* fc2W  = (const float*)d_in[13];
    const float* fc2b  = (const float*)d_in[14];
    float* out = (float*)d_out;

    // ---- workspace carve-up (256B aligned)
    char* p = (char*)d_ws;
    auto alloc = [&](size_t bytes) -> void* {
        void* r = (void*)p;
        p += (bytes + 255) & ~(size_t)255;
        return r;
    };
    float* dinv   = (float*)alloc((size_t)N_NODES * 4);        // deg -> dinv
    int*   counts = (int*)  alloc((size_t)(N_NODES + 1) * 4);
    int*   rowptr = (int*)  alloc((size_t)(N_NODES + 1) * 4);
    int*   cursor = (int*)  alloc((size_t)N_NODES * 4);
    int2*  col    = (int2*) alloc((size_t)N_EDGES * 8);        // (src, norm)
    int*   bsums  = (int*)  alloc(1024 * 4);
    float* stats  = (float*)alloc(512 * 4);                    // stats0 | stats1
    float* scsh1  = (float*)alloc(256 * 4);
    float* scsh2  = (float*)alloc(256 * 4);
    float* W2f    = (float*)alloc((size_t)NHID * NHID * 4);    // folded W2
    float* c2b    = (float*)alloc(256 * 4);                    // conv2 const row
    float* Wf     = (float*)alloc((size_t)(NFEAT + 2 * NHID) * NHID * 4); // folded fc1W
    float* bf     = (float*)alloc(256 * 4);                    // folded fc1 bias
    float* t_buf  = (float*)alloc((size_t)N_NODES * NHID * 4);
    float* h1     = (float*)alloc((size_t)N_NODES * NHID * 4);
    float* h2     = (float*)alloc((size_t)N_NODES * NHID * 4);

    const int gN1 = (N_NODES + 256) / 256;
    const int gE  = (N_EDGES + 255) / 256;
    const int gM  = (N_NODES + 127) / 128;

    // ---- graph preprocessing (CSR by dst, shared by both convs)
    init_kernel<<<gN1, 256, 0, stream>>>(counts, dinv, stats);
    hist_kernel<<<gE, 256, 0, stream>>>(adj, wt, counts, dinv);
    scan_block<<<SCAN_NB, 256, 0, stream>>>(counts, rowptr, bsums);
    scan_top<<<1, 512, 0, stream>>>(bsums);
    scan_add<<<SCAN_NB, 256, 0, stream>>>(rowptr, bsums, cursor, dinv);
    fill_kernel<<<gE, 256, 0, stream>>>(adj, wt, dinv, cursor, col);

    // ---- conv1: t = x@W1 ; h1 = relu(agg(t)+b1) ; BN1 stats -> scsh1
    gemm2<NHID, false><<<gM, 256, 0, stream>>>(x, W1, nullptr, t_buf, N_NODES, NFEAT);
    agg_kernel<<<(N_NODES + 3) / 4, 256, 0, stream>>>(t_buf, b1, dinv, rowptr, col, h1);
    stats_kernel<<<1024, 256, 0, stream>>>(h1, stats);
    bn_finalize<<<1, 128, 0, stream>>>(stats, g1, beta1, scsh1);

    // ---- conv2: t = h1@(sc1*W2) + sh1@W2 ; h2 = relu(agg(t)+b2) ; BN2 -> scsh2
    wfold2<<<1, 128, 0, stream>>>(W2, scsh1, W2f, c2b);
    gemm2<NHID, false><<<gM, 256, 0, stream>>>(h1, W2f, c2b, t_buf, N_NODES, NHID);
    agg_kernel<<<(N_NODES + 3) / 4, 256, 0, stream>>>(t_buf, b2, dinv, rowptr, col, h2);
    stats_kernel<<<1024, 256, 0, stream>>>(h2, stats + 256);
    bn_finalize<<<1, 128, 0, stream>>>(stats + 256, g2, beta2, scsh2);

    // ---- fc1 over concat, BN folded into Wf/bf
    fc1fold<<<2, 128, 0, stream>>>(fc1W, fc1b, scsh1, scsh2, Wf, bf);
    gemm_cat<<<gM, 256, 0, stream>>>(x, h1, h2, Wf, bf, t_buf, N_NODES);

    // ---- fc2: out = relu(t @ fc2W + fc2b)
    gemm2<NOUT, true><<<gM, 256, 0, stream>>>(t_buf, fc2W, fc2b, out, N_NODES, NHID);
}

// Round 14
// 1129.855 us; speedup vs baseline: 1.8597x; 1.8597x over previous
//
#include <hip/hip_runtime.h>
#include <hip/hip_bf16.h>

#define N_NODES 100000
#define N_EDGES 1600000
#define NFEAT   200
#define NHID    128
#define NOUT    64
#define BN_EPS  1e-5f

static constexpr int SCAN_NB = (N_NODES + 255) / 256;   // 391 blocks in level-1 scan

// ---------------------------------------------------------------- init
__global__ __launch_bounds__(256) void init_kernel(int* counts, float* deg, float* stats)
{
    int i = blockIdx.x * 256 + threadIdx.x;
    if (i <= N_NODES) counts[i] = 0;
    if (i <  N_NODES) deg[i]    = 1.0f;          // self-loop weight
    if (i <  512)     stats[i]  = 0.0f;          // stats0 (256) + stats1 (256)
}

// ------------------------------------------------------------ histogram
__global__ __launch_bounds__(256) void hist_kernel(const int* __restrict__ adj,
                                                   const float* __restrict__ wt,
                                                   int* __restrict__ counts,
                                                   float* __restrict__ deg)
{
    int e = blockIdx.x * 256 + threadIdx.x;
    if (e >= N_EDGES) return;
    int d = adj[N_EDGES + e];                     // dst row
    atomicAdd(&counts[d], 1);
    atomicAdd(&deg[d], wt[e]);
}

// ------------------------------------------------------- scan level 1
__global__ __launch_bounds__(256) void scan_block(const int* __restrict__ counts,
                                                  int* __restrict__ rowptr,
                                                  int* __restrict__ bsums)
{
    __shared__ int s[256];
    int t = threadIdx.x;
    int i = blockIdx.x * 256 + t;
    int v = (i < N_NODES) ? counts[i] : 0;
    s[t] = v; __syncthreads();
    #pragma unroll
    for (int off = 1; off < 256; off <<= 1) {
        int x = (t >= off) ? s[t - off] : 0;
        __syncthreads();
        s[t] += x;
        __syncthreads();
    }
    if (i < N_NODES) rowptr[i] = s[t] - v;        // block-local exclusive
    if (t == 255) bsums[blockIdx.x] = s[255];
}

// ------------------------------------------------------- scan level 2
__global__ __launch_bounds__(512) void scan_top(int* bsums)
{
    __shared__ int s[512];
    int t = threadIdx.x;
    int v = (t < SCAN_NB) ? bsums[t] : 0;
    s[t] = v; __syncthreads();
    #pragma unroll
    for (int off = 1; off < 512; off <<= 1) {
        int x = (t >= off) ? s[t - off] : 0;
        __syncthreads();
        s[t] += x;
        __syncthreads();
    }
    if (t < SCAN_NB) bsums[t] = s[t] - v;         // exclusive
}

// --------------------------------------- scan add + cursor + dinv fuse
__global__ __launch_bounds__(256) void scan_add(int* __restrict__ rowptr,
                                                const int* __restrict__ bsums,
                                                int* __restrict__ cursor,
                                                float* __restrict__ deg)
{
    int i = blockIdx.x * 256 + threadIdx.x;
    if (i < N_NODES) {
        int r = rowptr[i] + bsums[i >> 8];
        rowptr[i] = r;
        cursor[i] = r;
        float d = deg[i];
        deg[i] = (d > 0.f) ? rsqrtf(d) : 0.f;     // deg -> dinv in place
    }
    if (i == 0) rowptr[N_NODES] = N_EDGES;
}

// ------------------------------------------------------------ CSR fill
__global__ __launch_bounds__(256) void fill_kernel(const int* __restrict__ adj,
                                                   const float* __restrict__ wt,
                                                   const float* __restrict__ dinv,
                                                   int* __restrict__ cursor,
                                                   int2* __restrict__ col)
{
    int e = blockIdx.x * 256 + threadIdx.x;
    if (e >= N_EDGES) return;
    int s = adj[e];
    int d = adj[N_EDGES + e];
    int pos = atomicAdd(&cursor[d], 1);
    int2 c;
    c.x = s;
    c.y = __float_as_int(dinv[s] * wt[e] * dinv[d]);
    col[pos] = c;
}

// ------------------------------------------------------------- GEMM v3
// C[M,NC] = A[M,K] @ W[K,NC] (+bias if non-null) (+relu if RELU).
// BOTH tiles in LDS (round-10 lesson: global-broadcast A needs deep
// unroll to hide latency -> 248 VGPR -> 9% occupancy -> 25% VALU).
// A staged TRANSPOSED (a_t[k][m], +1 pad) so the inner loop reads A via
// ds_read_b128 like W (round-7 lesson: scalar ds_read_b32 A-reads made
// the kernel LDS-unit-bound: 70 LDS cyc vs 32 VALU cyc per kk per wave).
// Per wave per kk now: (RPT/4 + 2) b128 = 48 LDS cyc vs 128 VALU cyc.
template<int NC, bool RELU>
__global__ __launch_bounds__(256) void gemm3(const float* __restrict__ A,
                                             const float* __restrict__ W,
                                             const float* __restrict__ bias,
                                             float* __restrict__ C,
                                             int M, int K)
{
    constexpr int BK   = 64, BM = 128;
    constexpr int COLG = NC / 8;                 // 16 (NC=128) / 8 (NC=64)
    constexpr int RPT  = (BM * COLG) / 256;      // 8 / 4
    __shared__ float a_t[BK][BM + 1];            // transposed A tile, padded
    __shared__ float w_t[BK][NC];

    const int t    = threadIdx.x;
    const int m0   = blockIdx.x * BM;
    const int g    = t % COLG;
    const int c_lo = g * 4;
    const int c_hi = NC / 2 + c_lo;
    const int r0   = (t / COLG) * RPT;

    float acc[RPT][8];
    #pragma unroll
    for (int j = 0; j < RPT; ++j)
        #pragma unroll
        for (int i = 0; i < 8; ++i) acc[j][i] = 0.f;

    for (int k0 = 0; k0 < K; k0 += BK) {
        // ---- stage W[k0:k0+BK, :] (row-major, float4)
        constexpr int WF4 = BK * NC / 1024;      // 8 / 4
        #pragma unroll
        for (int i = 0; i < WF4; ++i) {
            int idx = t + i * 256;
            int kr  = idx / (NC / 4);
            int c4  = (idx % (NC / 4)) * 4;
            float4 v = make_float4(0.f, 0.f, 0.f, 0.f);
            if (k0 + kr < K) v = *(const float4*)&W[(size_t)(k0 + kr) * NC + c4];
            *(float4*)&w_t[kr][c4] = v;
        }
        // ---- stage A[m0:m0+BM, k0:k0+BK] transposed
        #pragma unroll
        for (int i = 0; i < BM * BK / 1024; ++i) {   // 8
            int idx = t + i * 256;
            int ar  = idx / (BK / 4);                // row in tile
            int ac  = (idx % (BK / 4)) * 4;          // k in tile
            float4 v = make_float4(0.f, 0.f, 0.f, 0.f);
            int m = m0 + ar, k = k0 + ac;
            if (m < M && k < K) v = *(const float4*)&A[(size_t)m * K + k];
            a_t[ac][ar]     = v.x;
            a_t[ac + 1][ar] = v.y;
            a_t[ac + 2][ar] = v.z;
            a_t[ac + 3][ar] = v.w;
        }
        __syncthreads();

        #pragma unroll 4
        for (int kk = 0; kk < BK; ++kk) {
            float4 a[RPT / 4];
            #pragma unroll
            for (int j4 = 0; j4 < RPT / 4; ++j4)
                a[j4] = *(const float4*)&a_t[kk][r0 + 4 * j4];
            float4 w0 = *(const float4*)&w_t[kk][c_lo];
            float4 w1 = *(const float4*)&w_t[kk][c_hi];
            #pragma unroll
            for (int j = 0; j < RPT; ++j) {
                float av = ((const float*)a)[j];
                acc[j][0] += av * w0.x; acc[j][1] += av * w0.y;
                acc[j][2] += av * w0.z; acc[j][3] += av * w0.w;
                acc[j][4] += av * w1.x; acc[j][5] += av * w1.y;
                acc[j][6] += av * w1.z; acc[j][7] += av * w1.w;
            }
        }
        __syncthreads();
    }

    float4 b0 = make_float4(0.f, 0.f, 0.f, 0.f);
    float4 b1 = make_float4(0.f, 0.f, 0.f, 0.f);
    if (bias) {
        b0 = *(const float4*)&bias[c_lo];
        b1 = *(const float4*)&bias[c_hi];
    }
    #pragma unroll
    for (int j = 0; j < RPT; ++j) {
        int m = m0 + r0 + j;
        if (m >= M) continue;
        float4 o0 = make_float4(acc[j][0] + b0.x, acc[j][1] + b0.y,
                                acc[j][2] + b0.z, acc[j][3] + b0.w);
        float4 o1 = make_float4(acc[j][4] + b1.x, acc[j][5] + b1.y,
                                acc[j][6] + b1.z, acc[j][7] + b1.w);
        if (RELU) {
            o0.x = fmaxf(o0.x, 0.f); o0.y = fmaxf(o0.y, 0.f);
            o0.z = fmaxf(o0.z, 0.f); o0.w = fmaxf(o0.w, 0.f);
            o1.x = fmaxf(o1.x, 0.f); o1.y = fmaxf(o1.y, 0.f);
            o1.z = fmaxf(o1.z, 0.f); o1.w = fmaxf(o1.w, 0.f);
        }
        *(float4*)&C[(size_t)m * NC + c_lo] = o0;
        *(float4*)&C[(size_t)m * NC + c_hi] = o1;
    }
}

// ----------------------------------------- fc1 concat GEMM (BN folded)
// C = relu([x | h1 | h2] @ Wf + bf). Same LDS structure as gemm3; the
// concat segment is chosen per staged float4 (boundaries 200/328/456
// are %4==0, so each float4 is segment-uniform).
__global__ __launch_bounds__(256) void gemm_cat3(const float* __restrict__ x,
                                                 const float* __restrict__ h1,
                                                 const float* __restrict__ h2,
                                                 const float* __restrict__ Wf,
                                                 const float* __restrict__ bf,
                                                 float* __restrict__ C, int M)
{
    constexpr int NC = NHID, BK = 64, BM = 128, KTOT = NFEAT + 2 * NHID;  // 456
    constexpr int COLG = 16, RPT = 8;
    __shared__ float a_t[BK][BM + 1];
    __shared__ float w_t[BK][NC];

    const int t    = threadIdx.x;
    const int m0   = blockIdx.x * BM;
    const int g    = t % COLG;
    const int c_lo = g * 4;
    const int c_hi = NC / 2 + c_lo;
    const int r0   = (t / COLG) * RPT;

    float acc[RPT][8];
    #pragma unroll
    for (int j = 0; j < RPT; ++j)
        #pragma unroll
        for (int i = 0; i < 8; ++i) acc[j][i] = 0.f;

    for (int k0 = 0; k0 < 512; k0 += BK) {
        #pragma unroll
        for (int i = 0; i < 8; ++i) {
            int idx = t + i * 256;
            int kr  = idx / (NC / 4);
            int c4  = (idx % (NC / 4)) * 4;
            float4 v = make_float4(0.f, 0.f, 0.f, 0.f);
            if (k0 + kr < KTOT) v = *(const float4*)&Wf[(size_t)(k0 + kr) * NC + c4];
            *(float4*)&w_t[kr][c4] = v;
        }
        #pragma unroll
        for (int i = 0; i < 8; ++i) {
            int idx = t + i * 256;
            int ar  = idx / (BK / 4);
            int ac  = (idx % (BK / 4)) * 4;
            int m   = m0 + ar, kc = k0 + ac;
            float4 v = make_float4(0.f, 0.f, 0.f, 0.f);
            if (m < M && kc < KTOT) {
                if (kc < NFEAT)             v = *(const float4*)&x [(size_t)m * NFEAT + kc];
                else if (kc < NFEAT + NHID) v = *(const float4*)&h1[(size_t)m * NHID + (kc - NFEAT)];
                else                        v = *(const float4*)&h2[(size_t)m * NHID + (kc - NFEAT - NHID)];
            }
            a_t[ac][ar]     = v.x;
            a_t[ac + 1][ar] = v.y;
            a_t[ac + 2][ar] = v.z;
            a_t[ac + 3][ar] = v.w;
        }
        __syncthreads();

        #pragma unroll 4
        for (int kk = 0; kk < BK; ++kk) {
            float4 a0 = *(const float4*)&a_t[kk][r0];
            float4 a1 = *(const float4*)&a_t[kk][r0 + 4];
            float4 w0 = *(const float4*)&w_t[kk][c_lo];
            float4 w1 = *(const float4*)&w_t[kk][c_hi];
            const float* ap0 = (const float*)&a0;
            const float* ap1 = (const float*)&a1;
            #pragma unroll
            for (int j = 0; j < 4; ++j) {
                float av = ap0[j];
                acc[j][0] += av * w0.x; acc[j][1] += av * w0.y;
                acc[j][2] += av * w0.z; acc[j][3] += av * w0.w;
                acc[j][4] += av * w1.x; acc[j][5] += av * w1.y;
                acc[j][6] += av * w1.z; acc[j][7] += av * w1.w;
            }
            #pragma unroll
            for (int j = 0; j < 4; ++j) {
                float av = ap1[j];
                acc[4 + j][0] += av * w0.x; acc[4 + j][1] += av * w0.y;
                acc[4 + j][2] += av * w0.z; acc[4 + j][3] += av * w0.w;
                acc[4 + j][4] += av * w1.x; acc[4 + j][5] += av * w1.y;
                acc[4 + j][6] += av * w1.z; acc[4 + j][7] += av * w1.w;
            }
        }
        __syncthreads();
    }

    float4 b0 = *(const float4*)&bf[c_lo];
    float4 b1 = *(const float4*)&bf[c_hi];
    #pragma unroll
    for (int j = 0; j < RPT; ++j) {
        int m = m0 + r0 + j;
        if (m >= M) continue;
        float4 o0 = make_float4(fmaxf(acc[j][0] + b0.x, 0.f), fmaxf(acc[j][1] + b0.y, 0.f),
                                fmaxf(acc[j][2] + b0.z, 0.f), fmaxf(acc[j][3] + b0.w, 0.f));
        float4 o1 = make_float4(fmaxf(acc[j][4] + b1.x, 0.f), fmaxf(acc[j][5] + b1.y, 0.f),
                                fmaxf(acc[j][6] + b1.z, 0.f), fmaxf(acc[j][7] + b1.w, 0.f));
        *(float4*)&C[(size_t)m * NC + c_lo] = o0;
        *(float4*)&C[(size_t)m * NC + c_hi] = o1;
    }
}

// ----------------------------- BN fold for conv2: W2f = diag(sc1)@W2,
// c2[c] = sum_k sh1[k]*W2[k][c]  (constant row, added as GEMM bias)
__global__ __launch_bounds__(128) void wfold2(const float* __restrict__ W2,
                                              const float* __restrict__ scsh1,
                                              float* __restrict__ W2f,
                                              float* __restrict__ c2)
{
    int c = threadIdx.x;                       // 0..127, single block
    float acc = 0.f;
    for (int k = 0; k < NHID; ++k) {
        float w = W2[k * NHID + c];
        W2f[k * NHID + c] = scsh1[k] * w;
        acc += scsh1[NHID + k] * w;
    }
    c2[c] = acc;
}

// ----------------------------- BN fold for fc1 concat weight + bias
__global__ __launch_bounds__(128) void fc1fold(const float* __restrict__ Wc,
                                               const float* __restrict__ fc1b,
                                               const float* __restrict__ scsh1,
                                               const float* __restrict__ scsh2,
                                               float* __restrict__ Wf,
                                               float* __restrict__ bf)
{
    int c = threadIdx.x;                       // 0..127, grid = 2
    if (blockIdx.x == 0) {                     // copy x-rows unchanged
        for (int k = 0; k < NFEAT; ++k)
            Wf[(size_t)k * NHID + c] = Wc[(size_t)k * NHID + c];
    } else {                                   // scale h-rows, build bias
        float acc = fc1b[c];
        for (int k = 0; k < NHID; ++k) {
            float w = Wc[(size_t)(NFEAT + k) * NHID + c];
            Wf[(size_t)(NFEAT + k) * NHID + c] = scsh1[k] * w;
            acc += scsh1[NHID + k] * w;
        }
        for (int k = 0; k < NHID; ++k) {
            float w = Wc[(size_t)(NFEAT + NHID + k) * NHID + c];
            Wf[(size_t)(NFEAT + NHID + k) * NHID + c] = scsh2[k] * w;
            acc += scsh2[NHID + k] * w;
        }
        bf[c] = acc;
    }
}

// --------------------------------------------------------- aggregation
// out[n,f] = relu( dinv[n]^2 * h[n,f] + sum_e norm[e]*h[src[e],f] + b[f] )
__global__ __launch_bounds__(256) void agg_kernel(const float* __restrict__ h,
                                                  const float* __restrict__ bias,
                                                  const float* __restrict__ dinv,
                                                  const int* __restrict__ rowptr,
                                                  const int2* __restrict__ col,
                                                  float* __restrict__ out)
{
    int node = blockIdx.x * 4 + (threadIdx.x >> 6);
    if (node >= N_NODES) return;
    int lane = threadIdx.x & 63;
    int f0 = lane * 2;

    float di = dinv[node];
    float2 hv = *(const float2*)&h[(size_t)node * NHID + f0];
    float ax = di * di * hv.x;
    float ay = di * di * hv.y;

    int e = rowptr[node], end = rowptr[node + 1];
    for (; e + 4 <= end; e += 4) {
        int2 c0 = col[e],     c1 = col[e + 1];
        int2 c2 = col[e + 2], c3 = col[e + 3];
        float2 v0 = *(const float2*)&h[(size_t)c0.x * NHID + f0];
        float2 v1 = *(const float2*)&h[(size_t)c1.x * NHID + f0];
        float2 v2 = *(const float2*)&h[(size_t)c2.x * NHID + f0];
        float2 v3 = *(const float2*)&h[(size_t)c3.x * NHID + f0];
        float n0 = __int_as_float(c0.y), n1 = __int_as_float(c1.y);
        float n2 = __int_as_float(c2.y), n3 = __int_as_float(c3.y);
        ax += n0 * v0.x + n1 * v1.x + n2 * v2.x + n3 * v3.x;
        ay += n0 * v0.y + n1 * v1.y + n2 * v2.y + n3 * v3.y;
    }
    for (; e < end; ++e) {
        int2 c = col[e];
        float2 v = *(const float2*)&h[(size_t)c.x * NHID + f0];
        float n = __int_as_float(c.y);
        ax += n * v.x;
        ay += n * v.y;
    }
    float2 b = *(const float2*)&bias[f0];
    float2 o;
    o.x = fmaxf(ax + b.x, 0.f);
    o.y = fmaxf(ay + b.y, 0.f);
    *(float2*)&out[(size_t)node * NHID + f0] = o;
}

// --------------------------------------------------------------- stats
__global__ __launch_bounds__(256) void stats_kernel(const float* __restrict__ h,
                                                    float* __restrict__ st)
{
    __shared__ float ls[256], ls2[256];
    int t = threadIdx.x;
    int c = t & 127, half = t >> 7;
    float s = 0.f, s2 = 0.f;
    for (int r = blockIdx.x * 2 + half; r < N_NODES; r += gridDim.x * 2) {
        float v = h[(size_t)r * NHID + c];
        s += v; s2 += v * v;
    }
    ls[t] = s; ls2[t] = s2; __syncthreads();
    if (half == 0) {
        s  += ls[t + 128];
        s2 += ls2[t + 128];
        atomicAdd(&st[c], s);
        atomicAdd(&st[128 + c], s2);
    }
}

// --------------------------------------------------------- bn finalize
__global__ __launch_bounds__(128) void bn_finalize(const float* __restrict__ st,
                                                   const float* __restrict__ g,
                                                   const float* __restrict__ beta,
                                                   float* __restrict__ scsh)
{
    int c = threadIdx.x;
    float mean = st[c] / (float)N_NODES;
    float var  = st[128 + c] / (float)N_NODES - mean * mean;
    float inv  = rsqrtf(var + BN_EPS);
    float sc   = g[c] * inv;
    scsh[c]        = sc;
    scsh[NHID + c] = beta[c] - mean * sc;
}

// ---------------------------------------------------------------- host
extern "C" void kernel_launch(void* const* d_in, const int* in_sizes, int n_in,
                              void* d_out, int out_size, void* d_ws, size_t ws_size,
                              hipStream_t stream)
{
    const float* x     = (const float*)d_in[0];
    const int*   adj   = (const int*)d_in[1];
    const float* wt    = (const float*)d_in[2];
    const float* W1    = (const float*)d_in[3];
    const float* b1    = (const float*)d_in[4];
    const float* W2    = (const float*)d_in[5];
    const float* b2    = (const float*)d_in[6];
    const float* g1    = (const float*)d_in[7];
    const float* beta1 = (const float*)d_in[8];
    const float* g2    = (const float*)d_in[9];
    const float* beta2 = (const float*)d_in[10];
    const float* fc1W  = (const float*)d_in[11];
    const float* fc1b  = (const float*)d_in[12];
    const float* fc2W  = (const float*)d_in[13];
    const float* fc2b  = (const float*)d_in[14];
    float* out = (float*)d_out;

    // ---- workspace carve-up (256B aligned)
    char* p = (char*)d_ws;
    auto alloc = [&](size_t bytes) -> void* {
        void* r = (void*)p;
        p += (bytes + 255) & ~(size_t)255;
        return r;
    };
    float* dinv   = (float*)alloc((size_t)N_NODES * 4);        // deg -> dinv
    int*   counts = (int*)  alloc((size_t)(N_NODES + 1) * 4);
    int*   rowptr = (int*)  alloc((size_t)(N_NODES + 1) * 4);
    int*   cursor = (int*)  alloc((size_t)N_NODES * 4);
    int2*  col    = (int2*) alloc((size_t)N_EDGES * 8);        // (src, norm)
    int*   bsums  = (int*)  alloc(1024 * 4);
    float* stats  = (float*)alloc(512 * 4);                    // stats0 | stats1
    float* scsh1  = (float*)alloc(256 * 4);
    float* scsh2  = (float*)alloc(256 * 4);
    float* W2f    = (float*)alloc((size_t)NHID * NHID * 4);    // folded W2
    float* c2b    = (float*)alloc(256 * 4);                    // conv2 const row
    float* Wf     = (float*)alloc((size_t)(NFEAT + 2 * NHID) * NHID * 4); // folded fc1W
    float* bf     = (float*)alloc(256 * 4);                    // folded fc1 bias
    float* t_buf  = (float*)alloc((size_t)N_NODES * NHID * 4);
    float* h1     = (float*)alloc((size_t)N_NODES * NHID * 4);
    float* h2     = (float*)alloc((size_t)N_NODES * NHID * 4);

    const int gN1 = (N_NODES + 256) / 256;
    const int gE  = (N_EDGES + 255) / 256;
    const int gM  = (N_NODES + 127) / 128;

    // ---- graph preprocessing (CSR by dst, shared by both convs)
    init_kernel<<<gN1, 256, 0, stream>>>(counts, dinv, stats);
    hist_kernel<<<gE, 256, 0, stream>>>(adj, wt, counts, dinv);
    scan_block<<<SCAN_NB, 256, 0, stream>>>(counts, rowptr, bsums);
    scan_top<<<1, 512, 0, stream>>>(bsums);
    scan_add<<<SCAN_NB, 256, 0, stream>>>(rowptr, bsums, cursor, dinv);
    fill_kernel<<<gE, 256, 0, stream>>>(adj, wt, dinv, cursor, col);

    // ---- conv1: t = x@W1 ; h1 = relu(agg(t)+b1) ; BN1 stats -> scsh1
    gemm3<NHID, false><<<gM, 256, 0, stream>>>(x, W1, nullptr, t_buf, N_NODES, NFEAT);
    agg_kernel<<<(N_NODES + 3) / 4, 256, 0, stream>>>(t_buf, b1, dinv, rowptr, col, h1);
    stats_kernel<<<1024, 256, 0, stream>>>(h1, stats);
    bn_finalize<<<1, 128, 0, stream>>>(stats, g1, beta1, scsh1);

    // ---- conv2: t = h1@(sc1*W2) + sh1@W2 ; h2 = relu(agg(t)+b2) ; BN2 -> scsh2
    wfold2<<<1, 128, 0, stream>>>(W2, scsh1, W2f, c2b);
    gemm3<NHID, false><<<gM, 256, 0, stream>>>(h1, W2f, c2b, t_buf, N_NODES, NHID);
    agg_kernel<<<(N_NODES + 3) / 4, 256, 0, stream>>>(t_buf, b2, dinv, rowptr, col, h2);
    stats_kernel<<<1024, 256, 0, stream>>>(h2, stats + 256);
    bn_finalize<<<1, 128, 0, stream>>>(stats + 256, g2, beta2, scsh2);

    // ---- fc1 over concat, BN folded into Wf/bf
    fc1fold<<<2, 128, 0, stream>>>(fc1W, fc1b, scsh1, scsh2, Wf, bf);
    gemm_cat3<<<gM, 256, 0, stream>>>(x, h1, h2, Wf, bf, t_buf, N_NODES);

    // ---- fc2: out = relu(t @ fc2W + fc2b)
    gemm3<NOUT, true><<<gM, 256, 0, stream>>>(t_buf, fc2W, fc2b, out, N_NODES, NHID);
}

// Round 15
// 1056.952 us; speedup vs baseline: 1.9880x; 1.0690x over previous
//
#include <hip/hip_runtime.h>
#include <hip/hip_bf16.h>

#define N_NODES 100000
#define N_EDGES 1600000
#define NFEAT   200
#define NHID    128
#define NOUT    64
#define BN_EPS  1e-5f

static constexpr int SCAN_NB = (N_NODES + 255) / 256;   // 391 blocks in level-1 scan

// ---------------------------------------------------------------- init
__global__ __launch_bounds__(256) void init_kernel(int* counts, float* deg, float* stats)
{
    int i = blockIdx.x * 256 + threadIdx.x;
    if (i <= N_NODES) counts[i] = 0;
    if (i <  N_NODES) deg[i]    = 1.0f;          // self-loop weight
    if (i <  512)     stats[i]  = 0.0f;          // stats0 (256) + stats1 (256)
}

// ------------------------------------------------------------ histogram
__global__ __launch_bounds__(256) void hist_kernel(const int* __restrict__ adj,
                                                   const float* __restrict__ wt,
                                                   int* __restrict__ counts,
                                                   float* __restrict__ deg)
{
    int e = blockIdx.x * 256 + threadIdx.x;
    if (e >= N_EDGES) return;
    int d = adj[N_EDGES + e];                     // dst row
    atomicAdd(&counts[d], 1);
    atomicAdd(&deg[d], wt[e]);
}

// ------------------------------------------------------- scan level 1
__global__ __launch_bounds__(256) void scan_block(const int* __restrict__ counts,
                                                  int* __restrict__ rowptr,
                                                  int* __restrict__ bsums)
{
    __shared__ int s[256];
    int t = threadIdx.x;
    int i = blockIdx.x * 256 + t;
    int v = (i < N_NODES) ? counts[i] : 0;
    s[t] = v; __syncthreads();
    #pragma unroll
    for (int off = 1; off < 256; off <<= 1) {
        int x = (t >= off) ? s[t - off] : 0;
        __syncthreads();
        s[t] += x;
        __syncthreads();
    }
    if (i < N_NODES) rowptr[i] = s[t] - v;        // block-local exclusive
    if (t == 255) bsums[blockIdx.x] = s[255];
}

// ------------------------------------------------------- scan level 2
__global__ __launch_bounds__(512) void scan_top(int* bsums)
{
    __shared__ int s[512];
    int t = threadIdx.x;
    int v = (t < SCAN_NB) ? bsums[t] : 0;
    s[t] = v; __syncthreads();
    #pragma unroll
    for (int off = 1; off < 512; off <<= 1) {
        int x = (t >= off) ? s[t - off] : 0;
        __syncthreads();
        s[t] += x;
        __syncthreads();
    }
    if (t < SCAN_NB) bsums[t] = s[t] - v;         // exclusive
}

// --------------------------------------- scan add + cursor + dinv fuse
__global__ __launch_bounds__(256) void scan_add(int* __restrict__ rowptr,
                                                const int* __restrict__ bsums,
                                                int* __restrict__ cursor,
                                                float* __restrict__ deg)
{
    int i = blockIdx.x * 256 + threadIdx.x;
    if (i < N_NODES) {
        int r = rowptr[i] + bsums[i >> 8];
        rowptr[i] = r;
        cursor[i] = r;
        float d = deg[i];
        deg[i] = (d > 0.f) ? rsqrtf(d) : 0.f;     // deg -> dinv in place
    }
    if (i == 0) rowptr[N_NODES] = N_EDGES;
}

// ------------------------------------------------------------ CSR fill
__global__ __launch_bounds__(256) void fill_kernel(const int* __restrict__ adj,
                                                   const float* __restrict__ wt,
                                                   const float* __restrict__ dinv,
                                                   int* __restrict__ cursor,
                                                   int2* __restrict__ col)
{
    int e = blockIdx.x * 256 + threadIdx.x;
    if (e >= N_EDGES) return;
    int s = adj[e];
    int d = adj[N_EDGES + e];
    int pos = atomicAdd(&cursor[d], 1);
    int2 c;
    c.x = s;
    c.y = __float_as_int(dinv[s] * wt[e] * dinv[d]);
    col[pos] = c;
}

// ------------------------------------------------------------- GEMM v4
// = gemm3 with BK 64->32. Round-14 counters: 66 KB LDS -> 2 blocks/CU ->
// Occupancy 15%, VALUBusy 42% -> barrier-exposed staging latency is ~58%
// of runtime. Halving BK halves LDS (33 KB -> 4 blocks/CU; NC=64 -> 6),
// so other blocks' compute covers each block's stage+barrier stall.
template<int NC, bool RELU>
__global__ __launch_bounds__(256) void gemm3(const float* __restrict__ A,
                                             const float* __restrict__ W,
                                             const float* __restrict__ bias,
                                             float* __restrict__ C,
                                             int M, int K)
{
    constexpr int BK   = 32, BM = 128;
    constexpr int COLG = NC / 8;                 // 16 (NC=128) / 8 (NC=64)
    constexpr int RPT  = (BM * COLG) / 256;      // 8 / 4
    __shared__ float a_t[BK][BM + 1];            // transposed A tile, padded
    __shared__ float w_t[BK][NC];

    const int t    = threadIdx.x;
    const int m0   = blockIdx.x * BM;
    const int g    = t % COLG;
    const int c_lo = g * 4;
    const int c_hi = NC / 2 + c_lo;
    const int r0   = (t / COLG) * RPT;

    float acc[RPT][8];
    #pragma unroll
    for (int j = 0; j < RPT; ++j)
        #pragma unroll
        for (int i = 0; i < 8; ++i) acc[j][i] = 0.f;

    for (int k0 = 0; k0 < K; k0 += BK) {
        // ---- stage W[k0:k0+BK, :] (row-major, float4)
        constexpr int WF4 = BK * NC / 1024;      // 4 / 2
        #pragma unroll
        for (int i = 0; i < WF4; ++i) {
            int idx = t + i * 256;
            int kr  = idx / (NC / 4);
            int c4  = (idx % (NC / 4)) * 4;
            float4 v = make_float4(0.f, 0.f, 0.f, 0.f);
            if (k0 + kr < K) v = *(const float4*)&W[(size_t)(k0 + kr) * NC + c4];
            *(float4*)&w_t[kr][c4] = v;
        }
        // ---- stage A[m0:m0+BM, k0:k0+BK] transposed
        #pragma unroll
        for (int i = 0; i < BM * BK / 1024; ++i) {   // 4
            int idx = t + i * 256;
            int ar  = idx / (BK / 4);                // row in tile
            int ac  = (idx % (BK / 4)) * 4;          // k in tile
            float4 v = make_float4(0.f, 0.f, 0.f, 0.f);
            int m = m0 + ar, k = k0 + ac;
            if (m < M && k < K) v = *(const float4*)&A[(size_t)m * K + k];
            a_t[ac][ar]     = v.x;
            a_t[ac + 1][ar] = v.y;
            a_t[ac + 2][ar] = v.z;
            a_t[ac + 3][ar] = v.w;
        }
        __syncthreads();

        #pragma unroll 4
        for (int kk = 0; kk < BK; ++kk) {
            float4 a[RPT / 4];
            #pragma unroll
            for (int j4 = 0; j4 < RPT / 4; ++j4)
                a[j4] = *(const float4*)&a_t[kk][r0 + 4 * j4];
            float4 w0 = *(const float4*)&w_t[kk][c_lo];
            float4 w1 = *(const float4*)&w_t[kk][c_hi];
            #pragma unroll
            for (int j = 0; j < RPT; ++j) {
                float av = ((const float*)a)[j];
                acc[j][0] += av * w0.x; acc[j][1] += av * w0.y;
                acc[j][2] += av * w0.z; acc[j][3] += av * w0.w;
                acc[j][4] += av * w1.x; acc[j][5] += av * w1.y;
                acc[j][6] += av * w1.z; acc[j][7] += av * w1.w;
            }
        }
        __syncthreads();
    }

    float4 b0 = make_float4(0.f, 0.f, 0.f, 0.f);
    float4 b1 = make_float4(0.f, 0.f, 0.f, 0.f);
    if (bias) {
        b0 = *(const float4*)&bias[c_lo];
        b1 = *(const float4*)&bias[c_hi];
    }
    #pragma unroll
    for (int j = 0; j < RPT; ++j) {
        int m = m0 + r0 + j;
        if (m >= M) continue;
        float4 o0 = make_float4(acc[j][0] + b0.x, acc[j][1] + b0.y,
                                acc[j][2] + b0.z, acc[j][3] + b0.w);
        float4 o1 = make_float4(acc[j][4] + b1.x, acc[j][5] + b1.y,
                                acc[j][6] + b1.z, acc[j][7] + b1.w);
        if (RELU) {
            o0.x = fmaxf(o0.x, 0.f); o0.y = fmaxf(o0.y, 0.f);
            o0.z = fmaxf(o0.z, 0.f); o0.w = fmaxf(o0.w, 0.f);
            o1.x = fmaxf(o1.x, 0.f); o1.y = fmaxf(o1.y, 0.f);
            o1.z = fmaxf(o1.z, 0.f); o1.w = fmaxf(o1.w, 0.f);
        }
        *(float4*)&C[(size_t)m * NC + c_lo] = o0;
        *(float4*)&C[(size_t)m * NC + c_hi] = o1;
    }
}

// ----------------------------------------- fc1 concat GEMM (BN folded)
// C = relu([x | h1 | h2] @ Wf + bf). BK=32 like gemm3; concat segment
// chosen per staged float4 (boundaries 200/328/456 are %4==0).
__global__ __launch_bounds__(256) void gemm_cat3(const float* __restrict__ x,
                                                 const float* __restrict__ h1,
                                                 const float* __restrict__ h2,
                                                 const float* __restrict__ Wf,
                                                 const float* __restrict__ bf,
                                                 float* __restrict__ C, int M)
{
    constexpr int NC = NHID, BK = 32, BM = 128, KTOT = NFEAT + 2 * NHID;  // 456
    constexpr int COLG = 16, RPT = 8;
    __shared__ float a_t[BK][BM + 1];
    __shared__ float w_t[BK][NC];

    const int t    = threadIdx.x;
    const int m0   = blockIdx.x * BM;
    const int g    = t % COLG;
    const int c_lo = g * 4;
    const int c_hi = NC / 2 + c_lo;
    const int r0   = (t / COLG) * RPT;

    float acc[RPT][8];
    #pragma unroll
    for (int j = 0; j < RPT; ++j)
        #pragma unroll
        for (int i = 0; i < 8; ++i) acc[j][i] = 0.f;

    for (int k0 = 0; k0 < 512; k0 += BK) {      // 16 tiles, covers 456 w/ pad
        #pragma unroll
        for (int i = 0; i < BK * NC / 1024; ++i) {   // 4
            int idx = t + i * 256;
            int kr  = idx / (NC / 4);
            int c4  = (idx % (NC / 4)) * 4;
            float4 v = make_float4(0.f, 0.f, 0.f, 0.f);
            if (k0 + kr < KTOT) v = *(const float4*)&Wf[(size_t)(k0 + kr) * NC + c4];
            *(float4*)&w_t[kr][c4] = v;
        }
        #pragma unroll
        for (int i = 0; i < BM * BK / 1024; ++i) {   // 4
            int idx = t + i * 256;
            int ar  = idx / (BK / 4);
            int ac  = (idx % (BK / 4)) * 4;
            int m   = m0 + ar, kc = k0 + ac;
            float4 v = make_float4(0.f, 0.f, 0.f, 0.f);
            if (m < M && kc < KTOT) {
                if (kc < NFEAT)             v = *(const float4*)&x [(size_t)m * NFEAT + kc];
                else if (kc < NFEAT + NHID) v = *(const float4*)&h1[(size_t)m * NHID + (kc - NFEAT)];
                else                        v = *(const float4*)&h2[(size_t)m * NHID + (kc - NFEAT - NHID)];
            }
            a_t[ac][ar]     = v.x;
            a_t[ac + 1][ar] = v.y;
            a_t[ac + 2][ar] = v.z;
            a_t[ac + 3][ar] = v.w;
        }
        __syncthreads();

        #pragma unroll 4
        for (int kk = 0; kk < BK; ++kk) {
            float4 a0 = *(const float4*)&a_t[kk][r0];
            float4 a1 = *(const float4*)&a_t[kk][r0 + 4];
            float4 w0 = *(const float4*)&w_t[kk][c_lo];
            float4 w1 = *(const float4*)&w_t[kk][c_hi];
            const float* ap0 = (const float*)&a0;
            const float* ap1 = (const float*)&a1;
            #pragma unroll
            for (int j = 0; j < 4; ++j) {
                float av = ap0[j];
                acc[j][0] += av * w0.x; acc[j][1] += av * w0.y;
                acc[j][2] += av * w0.z; acc[j][3] += av * w0.w;
                acc[j][4] += av * w1.x; acc[j][5] += av * w1.y;
                acc[j][6] += av * w1.z; acc[j][7] += av * w1.w;
            }
            #pragma unroll
            for (int j = 0; j < 4; ++j) {
                float av = ap1[j];
                acc[4 + j][0] += av * w0.x; acc[4 + j][1] += av * w0.y;
                acc[4 + j][2] += av * w0.z; acc[4 + j][3] += av * w0.w;
                acc[4 + j][4] += av * w1.x; acc[4 + j][5] += av * w1.y;
                acc[4 + j][6] += av * w1.z; acc[4 + j][7] += av * w1.w;
            }
        }
        __syncthreads();
    }

    float4 b0 = *(const float4*)&bf[c_lo];
    float4 b1 = *(const float4*)&bf[c_hi];
    #pragma unroll
    for (int j = 0; j < RPT; ++j) {
        int m = m0 + r0 + j;
        if (m >= M) continue;
        float4 o0 = make_float4(fmaxf(acc[j][0] + b0.x, 0.f), fmaxf(acc[j][1] + b0.y, 0.f),
                                fmaxf(acc[j][2] + b0.z, 0.f), fmaxf(acc[j][3] + b0.w, 0.f));
        float4 o1 = make_float4(fmaxf(acc[j][4] + b1.x, 0.f), fmaxf(acc[j][5] + b1.y, 0.f),
                                fmaxf(acc[j][6] + b1.z, 0.f), fmaxf(acc[j][7] + b1.w, 0.f));
        *(float4*)&C[(size_t)m * NC + c_lo] = o0;
        *(float4*)&C[(size_t)m * NC + c_hi] = o1;
    }
}

// ----------------------------- BN fold for conv2: W2f = diag(sc1)@W2,
// c2[c] = sum_k sh1[k]*W2[k][c]  (constant row, added as GEMM bias)
__global__ __launch_bounds__(128) void wfold2(const float* __restrict__ W2,
                                              const float* __restrict__ scsh1,
                                              float* __restrict__ W2f,
                                              float* __restrict__ c2)
{
    int c = threadIdx.x;                       // 0..127, single block
    float acc = 0.f;
    for (int k = 0; k < NHID; ++k) {
        float w = W2[k * NHID + c];
        W2f[k * NHID + c] = scsh1[k] * w;
        acc += scsh1[NHID + k] * w;
    }
    c2[c] = acc;
}

// ----------------------------- BN fold for fc1 concat weight + bias
__global__ __launch_bounds__(128) void fc1fold(const float* __restrict__ Wc,
                                               const float* __restrict__ fc1b,
                                               const float* __restrict__ scsh1,
                                               const float* __restrict__ scsh2,
                                               float* __restrict__ Wf,
                                               float* __restrict__ bf)
{
    int c = threadIdx.x;                       // 0..127, grid = 2
    if (blockIdx.x == 0) {                     // copy x-rows unchanged
        for (int k = 0; k < NFEAT; ++k)
            Wf[(size_t)k * NHID + c] = Wc[(size_t)k * NHID + c];
    } else {                                   // scale h-rows, build bias
        float acc = fc1b[c];
        for (int k = 0; k < NHID; ++k) {
            float w = Wc[(size_t)(NFEAT + k) * NHID + c];
            Wf[(size_t)(NFEAT + k) * NHID + c] = scsh1[k] * w;
            acc += scsh1[NHID + k] * w;
        }
        for (int k = 0; k < NHID; ++k) {
            float w = Wc[(size_t)(NFEAT + NHID + k) * NHID + c];
            Wf[(size_t)(NFEAT + NHID + k) * NHID + c] = scsh2[k] * w;
            acc += scsh2[NHID + k] * w;
        }
        bf[c] = acc;
    }
}

// --------------------------------------------------------- aggregation
// out[n,f] = relu( dinv[n]^2 * h[n,f] + sum_e norm[e]*h[src[e],f] + b[f] )
__global__ __launch_bounds__(256) void agg_kernel(const float* __restrict__ h,
                                                  const float* __restrict__ bias,
                                                  const float* __restrict__ dinv,
                                                  const int* __restrict__ rowptr,
                                                  const int2* __restrict__ col,
                                                  float* __restrict__ out)
{
    int node = blockIdx.x * 4 + (threadIdx.x >> 6);
    if (node >= N_NODES) return;
    int lane = threadIdx.x & 63;
    int f0 = lane * 2;

    float di = dinv[node];
    float2 hv = *(const float2*)&h[(size_t)node * NHID + f0];
    float ax = di * di * hv.x;
    float ay = di * di * hv.y;

    int e = rowptr[node], end = rowptr[node + 1];
    for (; e + 4 <= end; e += 4) {
        int2 c0 = col[e],     c1 = col[e + 1];
        int2 c2 = col[e + 2], c3 = col[e + 3];
        float2 v0 = *(const float2*)&h[(size_t)c0.x * NHID + f0];
        float2 v1 = *(const float2*)&h[(size_t)c1.x * NHID + f0];
        float2 v2 = *(const float2*)&h[(size_t)c2.x * NHID + f0];
        float2 v3 = *(const float2*)&h[(size_t)c3.x * NHID + f0];
        float n0 = __int_as_float(c0.y), n1 = __int_as_float(c1.y);
        float n2 = __int_as_float(c2.y), n3 = __int_as_float(c3.y);
        ax += n0 * v0.x + n1 * v1.x + n2 * v2.x + n3 * v3.x;
        ay += n0 * v0.y + n1 * v1.y + n2 * v2.y + n3 * v3.y;
    }
    for (; e < end; ++e) {
        int2 c = col[e];
        float2 v = *(const float2*)&h[(size_t)c.x * NHID + f0];
        float n = __int_as_float(c.y);
        ax += n * v.x;
        ay += n * v.y;
    }
    float2 b = *(const float2*)&bias[f0];
    float2 o;
    o.x = fmaxf(ax + b.x, 0.f);
    o.y = fmaxf(ay + b.y, 0.f);
    *(float2*)&out[(size_t)node * NHID + f0] = o;
}

// --------------------------------------------------------------- stats
__global__ __launch_bounds__(256) void stats_kernel(const float* __restrict__ h,
                                                    float* __restrict__ st)
{
    __shared__ float ls[256], ls2[256];
    int t = threadIdx.x;
    int c = t & 127, half = t >> 7;
    float s = 0.f, s2 = 0.f;
    for (int r = blockIdx.x * 2 + half; r < N_NODES; r += gridDim.x * 2) {
        float v = h[(size_t)r * NHID + c];
        s += v; s2 += v * v;
    }
    ls[t] = s; ls2[t] = s2; __syncthreads();
    if (half == 0) {
        s  += ls[t + 128];
        s2 += ls2[t + 128];
        atomicAdd(&st[c], s);
        atomicAdd(&st[128 + c], s2);
    }
}

// --------------------------------------------------------- bn finalize
__global__ __launch_bounds__(128) void bn_finalize(const float* __restrict__ st,
                                                   const float* __restrict__ g,
                                                   const float* __restrict__ beta,
                                                   float* __restrict__ scsh)
{
    int c = threadIdx.x;
    float mean = st[c] / (float)N_NODES;
    float var  = st[128 + c] / (float)N_NODES - mean * mean;
    float inv  = rsqrtf(var + BN_EPS);
    float sc   = g[c] * inv;
    scsh[c]        = sc;
    scsh[NHID + c] = beta[c] - mean * sc;
}

// ---------------------------------------------------------------- host
extern "C" void kernel_launch(void* const* d_in, const int* in_sizes, int n_in,
                              void* d_out, int out_size, void* d_ws, size_t ws_size,
                              hipStream_t stream)
{
    const float* x     = (const float*)d_in[0];
    const int*   adj   = (const int*)d_in[1];
    const float* wt    = (const float*)d_in[2];
    const float* W1    = (const float*)d_in[3];
    const float* b1    = (const float*)d_in[4];
    const float* W2    = (const float*)d_in[5];
    const float* b2    = (const float*)d_in[6];
    const float* g1    = (const float*)d_in[7];
    const float* beta1 = (const float*)d_in[8];
    const float* g2    = (const float*)d_in[9];
    const float* beta2 = (const float*)d_in[10];
    const float* fc1W  = (const float*)d_in[11];
    const float* fc1b  = (const float*)d_in[12];
    const float* fc2W  = (const float*)d_in[13];
    const float* fc2b  = (const float*)d_in[14];
    float* out = (float*)d_out;

    // ---- workspace carve-up (256B aligned)
    char* p = (char*)d_ws;
    auto alloc = [&](size_t bytes) -> void* {
        void* r = (void*)p;
        p += (bytes + 255) & ~(size_t)255;
        return r;
    };
    float* dinv   = (float*)alloc((size_t)N_NODES * 4);        // deg -> dinv
    int*   counts = (int*)  alloc((size_t)(N_NODES + 1) * 4);
    int*   rowptr = (int*)  alloc((size_t)(N_NODES + 1) * 4);
    int*   cursor = (int*)  alloc((size_t)N_NODES * 4);
    int2*  col    = (int2*) alloc((size_t)N_EDGES * 8);        // (src, norm)
    int*   bsums  = (int*)  alloc(1024 * 4);
    float* stats  = (float*)alloc(512 * 4);                    // stats0 | stats1
    float* scsh1  = (float*)alloc(256 * 4);
    float* scsh2  = (float*)alloc(256 * 4);
    float* W2f    = (float*)alloc((size_t)NHID * NHID * 4);    // folded W2
    float* c2b    = (float*)alloc(256 * 4);                    // conv2 const row
    float* Wf     = (float*)alloc((size_t)(NFEAT + 2 * NHID) * NHID * 4); // folded fc1W
    float* bf     = (float*)alloc(256 * 4);                    // folded fc1 bias
    float* t_buf  = (float*)alloc((size_t)N_NODES * NHID * 4);
    float* h1     = (float*)alloc((size_t)N_NODES * NHID * 4);
    float* h2     = (float*)alloc((size_t)N_NODES * NHID * 4);

    const int gN1 = (N_NODES + 256) / 256;
    const int gE  = (N_EDGES + 255) / 256;
    const int gM  = (N_NODES + 127) / 128;

    // ---- graph preprocessing (CSR by dst, shared by both convs)
    init_kernel<<<gN1, 256, 0, stream>>>(counts, dinv, stats);
    hist_kernel<<<gE, 256, 0, stream>>>(adj, wt, counts, dinv);
    scan_block<<<SCAN_NB, 256, 0, stream>>>(counts, rowptr, bsums);
    scan_top<<<1, 512, 0, stream>>>(bsums);
    scan_add<<<SCAN_NB, 256, 0, stream>>>(rowptr, bsums, cursor, dinv);
    fill_kernel<<<gE, 256, 0, stream>>>(adj, wt, dinv, cursor, col);

    // ---- conv1: t = x@W1 ; h1 = relu(agg(t)+b1) ; BN1 stats -> scsh1
    gemm3<NHID, false><<<gM, 256, 0, stream>>>(x, W1, nullptr, t_buf, N_NODES, NFEAT);
    agg_kernel<<<(N_NODES + 3) / 4, 256, 0, stream>>>(t_buf, b1, dinv, rowptr, col, h1);
    stats_kernel<<<1024, 256, 0, stream>>>(h1, stats);
    bn_finalize<<<1, 128, 0, stream>>>(stats, g1, beta1, scsh1);

    // ---- conv2: t = h1@(sc1*W2) + sh1@W2 ; h2 = relu(agg(t)+b2) ; BN2 -> scsh2
    wfold2<<<1, 128, 0, stream>>>(W2, scsh1, W2f, c2b);
    gemm3<NHID, false><<<gM, 256, 0, stream>>>(h1, W2f, c2b, t_buf, N_NODES, NHID);
    agg_kernel<<<(N_NODES + 3) / 4, 256, 0, stream>>>(t_buf, b2, dinv, rowptr, col, h2);
    stats_kernel<<<1024, 256, 0, stream>>>(h2, stats + 256);
    bn_finalize<<<1, 128, 0, stream>>>(stats + 256, g2, beta2, scsh2);

    // ---- fc1 over concat, BN folded into Wf/bf
    fc1fold<<<2, 128, 0, stream>>>(fc1W, fc1b, scsh1, scsh2, Wf, bf);
    gemm_cat3<<<gM, 256, 0, stream>>>(x, h1, h2, Wf, bf, t_buf, N_NODES);

    // ---- fc2: out = relu(t @ fc2W + fc2b)
    gemm3<NOUT, true><<<gM, 256, 0, stream>>>(t_buf, fc2W, fc2b, out, N_NODES, NHID);
}